// Round 7
// baseline (323.483 us; speedup 1.0000x reference)
//
#include <hip/hip_runtime.h>
#include <math.h>

#define BB 8
#define MI 16
#define NN 409600          // 640*640
#define CEPS 1e-12f
#define GPB 80             // blocks per image
#define NBLK (BB*GPB)      // 640 total blocks — co-resident by construction
#define PXB 5120           // pixels per block (80*5120 = 409600)
#define TPB 256

// ws layout (floats): [0..15] barrier ints (memset to 0 each call);
//   PS [b][blk][80]  kernel-pass partials (v = m*5+c; c<4 sums, c=4 count)
//   PP [b][blk][32]  pull-pass partials  (v = m*2+c; c=0 loss, c=1 count)
#define WS_PS   16
#define WS_PP   (WS_PS + NBLK*80)

__global__ __launch_bounds__(TPB, 3) void k_fused(
    const float* __restrict__ outputs, const int* __restrict__ gt_texts,
    const int* __restrict__ gt_kernels, float* __restrict__ ws,
    int* __restrict__ bar, float* __restrict__ out) {
  __shared__ float red[4][64][17];     // 17.4 KB, stride-17 conflict-free
  __shared__ float cbuf[4][MI];
  __shared__ float gpart[3][80];
  __shared__ float tot80[80];
  __shared__ float4 sG[MI];
  __shared__ float svalid[MI];
  __shared__ float part[8][32];
  __shared__ float tot32[32];

  const int gb = blockIdx.x;
  const int b = gb / GPB, blk = gb % GPB;
  const int tid = threadIdx.x, wv = tid >> 6, lane = tid & 63;
  const int mb = wv * 4;

  const float* s0 = outputs + (size_t)(b * 8 + 4) * NN;
  const int* gkb = gt_kernels + (size_t)b * NN;
  const int* ttb = gt_texts + (size_t)b * NN;

  // ---------- P1: kernel-pixel sums (id-split across waves, no atomics) ----
  float acc[16];                       // acc[c*4+j]: channel c, id mb+j
#pragma unroll
  for (int i = 0; i < 16; i++) acc[i] = 0.f;
  unsigned int cnt[4] = {0u, 0u, 0u, 0u};

#pragma unroll 4
  for (int it = 0; it < 20; it++) {
    const int pix = blk * PXB + it * 256 + lane * 4;
    const int4 id4 = *(const int4*)(gkb + pix);
    const float4 x0 = *(const float4*)(s0 + pix);
    const float4 x1 = *(const float4*)(s0 + NN + pix);
    const float4 x2 = *(const float4*)(s0 + 2 * NN + pix);
    const float4 x3 = *(const float4*)(s0 + 3 * NN + pix);
#define SLOTK(IDC, XC)                                                       \
    {                                                                        \
      const int id = id4.IDC - mb;                                           \
      _Pragma("unroll")                                                      \
      for (int j = 0; j < 4; j++) {                                          \
        const bool e = (id == j);                                            \
        cnt[j] += (unsigned)__popcll(__ballot(e));   /* scalar pipe */       \
        const float f = e ? 1.f : 0.f;                                       \
        acc[0 * 4 + j] += f * x0.XC;                                         \
        acc[1 * 4 + j] += f * x1.XC;                                         \
        acc[2 * 4 + j] += f * x2.XC;                                         \
        acc[3 * 4 + j] += f * x3.XC;                                         \
      }                                                                      \
    }
    SLOTK(x, x) SLOTK(y, y) SLOTK(z, z) SLOTK(w, w)
#undef SLOTK
  }

#pragma unroll
  for (int v = 0; v < 16; v++) red[wv][lane][v] = acc[v];
  if (lane == 0) {
#pragma unroll
    for (int j = 0; j < 4; j++) cbuf[0][mb + j] = (float)cnt[j];
  }
  __syncthreads();
  if (tid < 80) {
    const int m = tid / 5, c = tid % 5;
    const int w = m >> 2, j = m & 3;
    float s;
    if (c < 4) {
      const int vi = c * 4 + j;
      s = 0.f;
#pragma unroll 8
      for (int l = 0; l < 64; l++) s += red[w][(l + tid) & 63][vi];
    } else {
      s = cbuf[0][m];
    }
    ws[WS_PS + gb * 80 + tid] = s;     // coalesced, contiguous per block
  }

  // ---------- grid barrier 1 (all blocks need all PS partials) ------------
  __syncthreads();
  if (tid == 0) {
    __threadfence();                   // release PS writes device-wide
    atomicAdd(&bar[0], 1);
    while (__hip_atomic_load(&bar[0], __ATOMIC_RELAXED,
                             __HIP_MEMORY_SCOPE_AGENT) < NBLK)
      __builtin_amdgcn_s_sleep(32);
    __threadfence();                   // acquire
  }
  __syncthreads();

  // ---------- P2a: every block computes G + valid for its image in LDS ----
  if (tid < 240) {
    const int v = tid % 80, h = tid / 80;          // 3 groups: 27/27/26 rows
    const int k0 = (h == 0) ? 0 : (h == 1) ? 27 : 54;
    const int k1 = (h == 0) ? 27 : (h == 1) ? 54 : 80;
    float s = 0.f;
    for (int k = k0; k < k1; k++) s += ws[WS_PS + (b * GPB + k) * 80 + v];
    gpart[h][v] = s;
  }
  __syncthreads();
  if (tid < 80) tot80[tid] = gpart[0][tid] + gpart[1][tid] + gpart[2][tid];
  __syncthreads();
  if (tid < MI) {
    const float c5 = tot80[tid * 5 + 4];
    const float inv = 1.f / fmaxf(c5, 1.f);
    float4 g;
    g.x = tot80[tid * 5 + 0] * inv;
    g.y = tot80[tid * 5 + 1] * inv;
    g.z = tot80[tid * 5 + 2] * inv;
    g.w = tot80[tid * 5 + 3] * inv;
    sG[tid] = g;
    svalid[tid] = (c5 > 0.f && tid >= 1) ? 1.f : 0.f;
  }
  __syncthreads();

  // ---------- P2b: pull pass (dist/log once per pixel, no atomics) --------
  float al[16];
#pragma unroll
  for (int m = 0; m < MI; m++) al[m] = 0.f;
  unsigned int cw[16];
#pragma unroll
  for (int m = 0; m < MI; m++) cw[m] = 0u;

#pragma unroll
  for (int it = 0; it < 5; it++) {
    const int pix = blk * PXB + it * 1024 + tid * 4;
    const int4 id4 = *(const int4*)(ttb + pix);
    const float4 x0 = *(const float4*)(s0 + pix);
    const float4 x1 = *(const float4*)(s0 + NN + pix);
    const float4 x2 = *(const float4*)(s0 + 2 * NN + pix);
    const float4 x3 = *(const float4*)(s0 + 3 * NN + pix);
#define SLOTP(IDC, XC)                                                       \
    {                                                                        \
      const int id = id4.IDC;                                                \
      const float4 g = sG[id];                                               \
      const float d0 = x0.XC - g.x, d1 = x1.XC - g.y;                        \
      const float d2 = x2.XC - g.z, d3 = x3.XC - g.w;                        \
      const float dist = sqrtf(d0*d0 + d1*d1 + d2*d2 + d3*d3 + CEPS) - 0.5f; \
      const float dm = fmaxf(dist, 0.f);                                     \
      const float l = __logf(1.f + dm * dm);                                 \
      _Pragma("unroll")                                                      \
      for (int m = 0; m < MI; m++) {                                         \
        const bool e = (id == m);                                            \
        cw[m] += (unsigned)__popcll(__ballot(e));    /* scalar pipe */       \
        al[m] += e ? l : 0.f;                                                \
      }                                                                      \
    }
    SLOTP(x, x) SLOTP(y, y) SLOTP(z, z) SLOTP(w, w)
#undef SLOTP
  }

  __syncthreads();                     // red[] reuse after P1
#pragma unroll
  for (int v = 0; v < 16; v++) red[wv][lane][v] = al[v];
  if (lane == 0) {
#pragma unroll
    for (int m = 0; m < MI; m++) cbuf[wv][m] = (float)cw[m];
  }
  __syncthreads();
  if (tid < 32) {
    const int m = tid >> 1, c = tid & 1;
    float s = 0.f;
    if (c == 0) {
#pragma unroll
      for (int w = 0; w < 4; w++)
#pragma unroll 8
        for (int l = 0; l < 64; l++) s += red[w][(l + tid) & 63][m];
    } else {
      s = cbuf[0][m] + cbuf[1][m] + cbuf[2][m] + cbuf[3][m];
    }
    ws[WS_PP + gb * 32 + tid] = s;
  }

  // ---------- grid barrier 2 (arrive all; only finalizers wait) -----------
  __syncthreads();
  if (tid == 0) {
    __threadfence();
    atomicAdd(&bar[1], 1);
    if (blk == 0) {
      while (__hip_atomic_load(&bar[1], __ATOMIC_RELAXED,
                               __HIP_MEMORY_SCOPE_AGENT) < NBLK)
        __builtin_amdgcn_s_sleep(32);
      __threadfence();
    }
  }
  if (blk != 0) return;                // non-finalizers exit
  __syncthreads();

  // ---------- P3: one block per image finalizes -----------------------------
  {
    const int v = tid & 31, h = tid >> 5;          // 8 groups of 10 rows
    float s = 0.f;
#pragma unroll 5
    for (int k = 0; k < 10; k++)
      s += ws[WS_PP + (b * GPB + h * 10 + k) * 32 + v];
    part[h][v] = s;
  }
  __syncthreads();
  if (tid < 32) {
    float x = 0.f;
#pragma unroll
    for (int hh = 0; hh < 8; hh++) x += part[hh][tid];
    tot32[tid] = x;
  }
  __syncthreads();
  if (tid == 0) {
    float nv = 0.f;
    for (int m = 0; m < MI; m++) nv += svalid[m];
    float pull = 0.f;
    for (int m = 0; m < MI; m++) {
      const float per = tot32[m * 2] / fmaxf(tot32[m * 2 + 1], 1.f);
      pull += per * svalid[m];
    }
    pull /= fmaxf(nv, 1.f);
    float push = 0.f;
    for (int i = 0; i < MI; i++) {
      if (svalid[i] == 0.f) continue;
      for (int j = i + 1; j < MI; j++) {
        if (svalid[j] == 0.f) continue;
        const float4 gi = sG[i], gj = sG[j];
        float d2 = CEPS;
        d2 += (gi.x - gj.x) * (gi.x - gj.x);
        d2 += (gi.y - gj.y) * (gi.y - gj.y);
        d2 += (gi.z - gj.z) * (gi.z - gj.z);
        d2 += (gi.w - gj.w) * (gi.w - gj.w);
        const float dk = sqrtf(d2);
        const float tq = fmaxf(3.f - dk, 0.f);
        push += log1pf(tq * tq);
      }
    }
    const float denom = nv * (nv - 1.f);
    push = (nv > 1.f) ? push / fmaxf(denom, 1.f) : 0.f;
    out[b] = pull;
    out[BB + b] = push;
  }
}

extern "C" void kernel_launch(void* const* d_in, const int* in_sizes, int n_in,
                              void* d_out, int out_size, void* d_ws, size_t ws_size,
                              hipStream_t stream) {
  const float* outputs = (const float*)d_in[0];
  const int* gt_texts = (const int*)d_in[1];
  const int* gt_kernels = (const int*)d_in[2];
  float* ws = (float*)d_ws;
  int* bar = (int*)d_ws;               // first 16 floats reserved for barriers
  float* out = (float*)d_out;

  hipMemsetAsync(d_ws, 0, 16 * sizeof(float), stream);   // zero barrier ctrs
  k_fused<<<NBLK, TPB, 0, stream>>>(outputs, gt_texts, gt_kernels,
                                    ws, bar, out);
}

// Round 8
// 282.680 us; speedup vs baseline: 1.1443x; 1.1443x over previous
//
#include <hip/hip_runtime.h>
#include <math.h>

#define BB 8
#define MI 16
#define NN 409600          // 640*640
#define CEPS 1e-12f
#define GPB 100            // blocks per image (both passes); 4096 px/block
#define TPB 256

// ws float layout — zeroing done by kernel A block 0 (no memset dispatch):
//   PS  [b][blk][80]  kernel-pass partials (v = m*5+c; c<4 sums, c=4 count)
//   ACC [b][32]       pull-pass atomic accumulators (v = m*2+c)
//   DONE[b]           int tickets (after ACC)
#define WS_PS    0
#define WS_ACC   (BB*GPB*80)           // 64000
#define WS_DONEI (WS_ACC + BB*32)      // int index into ws

// Kernel A: kernel-pixel sums. Wave wv owns ids 4wv..4wv+3 (16 acc VGPRs);
// every wave streams the whole 4096-px chunk (redundant reads L1-absorbed).
// Counts ride the scalar pipe via ballot+popc. No atomics.
__global__ __launch_bounds__(TPB) void k_sums(
    const float* __restrict__ outputs, const int* __restrict__ gt_kernels,
    float* __restrict__ ws) {
  __shared__ float red[4][64][17];     // stride-17: conflict-free columns
  __shared__ float cbufA[MI];
  const int b = blockIdx.y, blk = blockIdx.x, tid = threadIdx.x;
  const int wv = tid >> 6, lane = tid & 63, mb = wv * 4;

  float acc[16];                       // acc[c*4+j]: channel c, id mb+j
#pragma unroll
  for (int i = 0; i < 16; i++) acc[i] = 0.f;
  unsigned int cnt[4] = {0u, 0u, 0u, 0u};

  const float* s0 = outputs + (size_t)(b * 8 + 4) * NN;
  const int* gkb = gt_kernels + (size_t)b * NN;

#pragma unroll 4
  for (int it = 0; it < 16; it++) {
    const int pix = blk * 4096 + it * 256 + lane * 4;
    const int4 id4 = *(const int4*)(gkb + pix);
    const float4 x0 = *(const float4*)(s0 + pix);
    const float4 x1 = *(const float4*)(s0 + NN + pix);
    const float4 x2 = *(const float4*)(s0 + 2 * NN + pix);
    const float4 x3 = *(const float4*)(s0 + 3 * NN + pix);
#define SLOTK(IDC, XC)                                                       \
    {                                                                        \
      const int id = id4.IDC - mb;                                           \
      _Pragma("unroll")                                                      \
      for (int j = 0; j < 4; j++) {                                          \
        const bool e = (id == j);                                            \
        cnt[j] += (unsigned)__popcll(__ballot(e));   /* scalar pipe */       \
        const float f = e ? 1.f : 0.f;                                       \
        acc[0 * 4 + j] += f * x0.XC;                                         \
        acc[1 * 4 + j] += f * x1.XC;                                         \
        acc[2 * 4 + j] += f * x2.XC;                                         \
        acc[3 * 4 + j] += f * x3.XC;                                         \
      }                                                                      \
    }
    SLOTK(x, x) SLOTK(y, y) SLOTK(z, z) SLOTK(w, w)
#undef SLOTK
  }

#pragma unroll
  for (int v = 0; v < 16; v++) red[wv][lane][v] = acc[v];
  if (lane == 0) {
#pragma unroll
    for (int j = 0; j < 4; j++) cbufA[mb + j] = (float)cnt[j];
  }
  __syncthreads();
  if (tid < 80) {
    const int m = tid / 5, c = tid % 5;
    const int w = m >> 2, j = m & 3;
    float s;
    if (c < 4) {
      const int vi = c * 4 + j;
      s = 0.f;
#pragma unroll 8
      for (int l = 0; l < 64; l++) s += red[w][(l + tid) & 63][vi];
    } else {
      s = cbufA[m];
    }
    ws[WS_PS + (size_t)(b * GPB + blk) * 80 + tid] = s;   // coalesced
  }
  // zero the cross-kernel atomic region (visible to B via dispatch boundary)
  if (blk == 0) {
    if (tid < 32) ws[WS_ACC + b * 32 + tid] = 0.f;
    else if (tid == 32) ((int*)ws)[WS_DONEI + b] = 0;
  }
}

// Kernel B: G from PS partials (per-block, L2-hot) + pull pass + atomic
// finalization (last ticket per image finalizes). No fences anywhere.
__global__ __launch_bounds__(TPB) void k_pullfin(
    const float* __restrict__ outputs, const int* __restrict__ gt_texts,
    float* __restrict__ ws, float* __restrict__ out) {
  __shared__ float red[4][64][17];
  __shared__ float cbuf[4][MI];
  __shared__ float gpart[3][80];
  __shared__ float tot80[80];
  __shared__ float4 sG[MI];
  __shared__ float svalid[MI];
  __shared__ float tot32[32];
  __shared__ int lastFlag;
  const int b = blockIdx.y, blk = blockIdx.x, tid = threadIdx.x;
  const int wv = tid >> 6, lane = tid & 63;
  if (tid == 0) lastFlag = 0;

  // ---- G + valid from PS partials (reads are L2/L3-hot, coalesced) ----
  if (tid < 240) {
    const int v = tid % 80, h = tid / 80;          // rows 34/34/32
    const int k0 = h * 34, k1 = (h == 2) ? GPB : k0 + 34;
    float s = 0.f;
    for (int k = k0; k < k1; k++)
      s += ws[WS_PS + (size_t)(b * GPB + k) * 80 + v];
    gpart[h][v] = s;
  }
  __syncthreads();
  if (tid < 80) tot80[tid] = gpart[0][tid] + gpart[1][tid] + gpart[2][tid];
  __syncthreads();
  if (tid < MI) {
    const float c5 = tot80[tid * 5 + 4];
    const float inv = 1.f / fmaxf(c5, 1.f);
    float4 g;
    g.x = tot80[tid * 5 + 0] * inv;
    g.y = tot80[tid * 5 + 1] * inv;
    g.z = tot80[tid * 5 + 2] * inv;
    g.w = tot80[tid * 5 + 3] * inv;
    sG[tid] = g;
    svalid[tid] = (c5 > 0.f && tid >= 1) ? 1.f : 0.f;
  }
  __syncthreads();

  // ---- pull pass: dist/log once per pixel, register accumulators ----
  float al[16];
#pragma unroll
  for (int m = 0; m < MI; m++) al[m] = 0.f;
  unsigned int cw[16];
#pragma unroll
  for (int m = 0; m < MI; m++) cw[m] = 0u;

  const float* s0 = outputs + (size_t)(b * 8 + 4) * NN;
  const int* ttb = gt_texts + (size_t)b * NN;

#pragma unroll
  for (int it = 0; it < 4; it++) {
    const int pix = blk * 4096 + it * 1024 + tid * 4;
    const int4 id4 = *(const int4*)(ttb + pix);
    const float4 x0 = *(const float4*)(s0 + pix);
    const float4 x1 = *(const float4*)(s0 + NN + pix);
    const float4 x2 = *(const float4*)(s0 + 2 * NN + pix);
    const float4 x3 = *(const float4*)(s0 + 3 * NN + pix);
#define SLOTP(IDC, XC)                                                       \
    {                                                                        \
      const int id = id4.IDC;                                                \
      const float4 g = sG[id];                                               \
      const float d0 = x0.XC - g.x, d1 = x1.XC - g.y;                        \
      const float d2 = x2.XC - g.z, d3 = x3.XC - g.w;                        \
      const float dist = sqrtf(d0*d0 + d1*d1 + d2*d2 + d3*d3 + CEPS) - 0.5f; \
      const float dm = fmaxf(dist, 0.f);                                     \
      const float l = __logf(1.f + dm * dm);                                 \
      _Pragma("unroll")                                                      \
      for (int m = 0; m < MI; m++) {                                         \
        const bool e = (id == m);                                            \
        cw[m] += (unsigned)__popcll(__ballot(e));    /* scalar pipe */       \
        al[m] += e ? l : 0.f;                                                \
      }                                                                      \
    }
    SLOTP(x, x) SLOTP(y, y) SLOTP(z, z) SLOTP(w, w)
#undef SLOTP
  }

  __syncthreads();                     // red[] reuse
#pragma unroll
  for (int v = 0; v < 16; v++) red[wv][lane][v] = al[v];
  if (lane == 0) {
#pragma unroll
    for (int m = 0; m < MI; m++) cbuf[wv][m] = (float)cw[m];
  }
  __syncthreads();

  // ---- 32 block-partials -> device-scope atomic accumulators ----
  if (tid < 32) {
    const int m = tid >> 1, c = tid & 1;
    float s = 0.f;
    if (c == 0) {
#pragma unroll
      for (int w = 0; w < 4; w++)
#pragma unroll 8
        for (int l = 0; l < 64; l++) s += red[w][(l + tid) & 63][m];
    } else {
      s = cbuf[0][m] + cbuf[1][m] + cbuf[2][m] + cbuf[3][m];
    }
    const float old = atomicAdd(&ws[WS_ACC + b * 32 + tid], s);
    if (old == -1.23456789e33f) ws[WS_ACC + b * 32 + tid] = 0.f;  // forces wait on completion
  }
  __builtin_amdgcn_s_waitcnt(0);       // adds at coherence point before ticket
  if (tid == 0) {
    const int t = atomicAdd(&((int*)ws)[WS_DONEI + b], 1);
    if (t == GPB - 1) lastFlag = 1;    // all blocks' adds have landed
  }
  __syncthreads();
  if (!lastFlag) return;

  // ---- last block per image finalizes (G/valid already in LDS) ----
  if (tid < 32)
    tot32[tid] = __hip_atomic_load(&ws[WS_ACC + b * 32 + tid],
                                   __ATOMIC_RELAXED, __HIP_MEMORY_SCOPE_AGENT);
  __syncthreads();
  if (tid == 0) {
    float nv = 0.f;
    for (int m = 0; m < MI; m++) nv += svalid[m];
    float pull = 0.f;
    for (int m = 0; m < MI; m++) {
      const float per = tot32[m * 2] / fmaxf(tot32[m * 2 + 1], 1.f);
      pull += per * svalid[m];
    }
    pull /= fmaxf(nv, 1.f);
    float push = 0.f;
    for (int i = 0; i < MI; i++) {
      if (svalid[i] == 0.f) continue;
      for (int j = i + 1; j < MI; j++) {
        if (svalid[j] == 0.f) continue;
        const float4 gi = sG[i], gj = sG[j];
        float d2 = CEPS;
        d2 += (gi.x - gj.x) * (gi.x - gj.x);
        d2 += (gi.y - gj.y) * (gi.y - gj.y);
        d2 += (gi.z - gj.z) * (gi.z - gj.z);
        d2 += (gi.w - gj.w) * (gi.w - gj.w);
        const float dk = sqrtf(d2);
        const float tq = fmaxf(3.f - dk, 0.f);
        push += log1pf(tq * tq);
      }
    }
    const float denom = nv * (nv - 1.f);
    push = (nv > 1.f) ? push / fmaxf(denom, 1.f) : 0.f;
    out[b] = pull;
    out[BB + b] = push;
  }
}

extern "C" void kernel_launch(void* const* d_in, const int* in_sizes, int n_in,
                              void* d_out, int out_size, void* d_ws, size_t ws_size,
                              hipStream_t stream) {
  const float* outputs = (const float*)d_in[0];
  const int* gt_texts = (const int*)d_in[1];
  const int* gt_kernels = (const int*)d_in[2];
  float* ws = (float*)d_ws;
  float* out = (float*)d_out;

  dim3 grid(GPB, BB);
  k_sums<<<grid, TPB, 0, stream>>>(outputs, gt_kernels, ws);
  k_pullfin<<<grid, TPB, 0, stream>>>(outputs, gt_texts, ws, out);
}

// Round 9
// 264.731 us; speedup vs baseline: 1.2219x; 1.0678x over previous
//
#include <hip/hip_runtime.h>
#include <math.h>

#define BB 8
#define MI 16
#define NN 409600          // 640*640
#define CEPS 1e-12f
#define GPB 100            // blocks per image (both passes); 4096 px/block
#define TPB 256

// ws float layout — no zero-init, no atomics (every slot stored before read):
//   PS  [b][blk][80]  kernel-pass partials (v = m*5+c; c<4 sums, c=4 count)
//   PP  [b][blk][32]  pull-pass partials  (v = m*2+c; c=0 loss, c=1 count)
//   G   [b][m][4], VAL [b][m]  (written by k_pull blk==0 for k_final)
#define WS_PS   0
#define WS_PP   (BB*GPB*80)            // 64000
#define WS_G    (WS_PP + BB*GPB*32)    // 89600
#define WS_VAL  (WS_G + BB*MI*4)       // 90112

// Kernel A: kernel-pixel sums. Wave wv owns ids 4wv..4wv+3 (16 acc VGPRs);
// every wave streams the whole 4096-px chunk (redundant reads L1-absorbed).
// Counts ride the scalar pipe via ballot+popc. No atomics.
__global__ __launch_bounds__(TPB) void k_sums(
    const float* __restrict__ outputs, const int* __restrict__ gt_kernels,
    float* __restrict__ ws) {
  __shared__ float red[4][64][17];     // stride-17: conflict-free columns
  __shared__ float cbufA[MI];
  const int b = blockIdx.y, blk = blockIdx.x, tid = threadIdx.x;
  const int wv = tid >> 6, lane = tid & 63, mb = wv * 4;

  float acc[16];                       // acc[c*4+j]: channel c, id mb+j
#pragma unroll
  for (int i = 0; i < 16; i++) acc[i] = 0.f;
  unsigned int cnt[4] = {0u, 0u, 0u, 0u};

  const float* s0 = outputs + (size_t)(b * 8 + 4) * NN;
  const int* gkb = gt_kernels + (size_t)b * NN;

#pragma unroll 4
  for (int it = 0; it < 16; it++) {
    const int pix = blk * 4096 + it * 256 + lane * 4;
    const int4 id4 = *(const int4*)(gkb + pix);
    const float4 x0 = *(const float4*)(s0 + pix);
    const float4 x1 = *(const float4*)(s0 + NN + pix);
    const float4 x2 = *(const float4*)(s0 + 2 * NN + pix);
    const float4 x3 = *(const float4*)(s0 + 3 * NN + pix);
#define SLOTK(IDC, XC)                                                       \
    {                                                                        \
      const int id = id4.IDC - mb;                                           \
      _Pragma("unroll")                                                      \
      for (int j = 0; j < 4; j++) {                                          \
        const bool e = (id == j);                                            \
        cnt[j] += (unsigned)__popcll(__ballot(e));   /* scalar pipe */       \
        const float f = e ? 1.f : 0.f;                                       \
        acc[0 * 4 + j] += f * x0.XC;                                         \
        acc[1 * 4 + j] += f * x1.XC;                                         \
        acc[2 * 4 + j] += f * x2.XC;                                         \
        acc[3 * 4 + j] += f * x3.XC;                                         \
      }                                                                      \
    }
    SLOTK(x, x) SLOTK(y, y) SLOTK(z, z) SLOTK(w, w)
#undef SLOTK
  }

#pragma unroll
  for (int v = 0; v < 16; v++) red[wv][lane][v] = acc[v];
  if (lane == 0) {
#pragma unroll
    for (int j = 0; j < 4; j++) cbufA[mb + j] = (float)cnt[j];
  }
  __syncthreads();
  if (tid < 80) {
    const int m = tid / 5, c = tid % 5;
    const int w = m >> 2, j = m & 3;
    float s;
    if (c < 4) {
      const int vi = c * 4 + j;
      s = 0.f;
#pragma unroll 8
      for (int l = 0; l < 64; l++) s += red[w][(l + tid) & 63][vi];
    } else {
      s = cbufA[m];
    }
    ws[WS_PS + (size_t)(b * GPB + blk) * 80 + tid] = s;   // coalesced
  }
}

// Kernel B: per-block G from PS partials (L2/L3-hot), pull pass, partials
// to distinct slots. blk==0 publishes G/valid for k_final. No atomics.
__global__ __launch_bounds__(TPB) void k_pull(
    const float* __restrict__ outputs, const int* __restrict__ gt_texts,
    float* __restrict__ ws) {
  __shared__ float red[4][64][17];
  __shared__ float cbuf[4][MI];
  __shared__ float gpart[3][80];
  __shared__ float tot80[80];
  __shared__ float4 sG[MI];
  __shared__ float svalid[MI];
  const int b = blockIdx.y, blk = blockIdx.x, tid = threadIdx.x;
  const int wv = tid >> 6, lane = tid & 63;

  // ---- G + valid from PS partials (coalesced, 3×~34 rows) ----
  if (tid < 240) {
    const int v = tid % 80, h = tid / 80;          // rows 34/34/32
    const int k0 = h * 34, k1 = (h == 2) ? GPB : k0 + 34;
    float s = 0.f;
    for (int k = k0; k < k1; k++)
      s += ws[WS_PS + (size_t)(b * GPB + k) * 80 + v];
    gpart[h][v] = s;
  }
  __syncthreads();
  if (tid < 80) tot80[tid] = gpart[0][tid] + gpart[1][tid] + gpart[2][tid];
  __syncthreads();
  if (tid < MI) {
    const float c5 = tot80[tid * 5 + 4];
    const float inv = 1.f / fmaxf(c5, 1.f);
    float4 g;
    g.x = tot80[tid * 5 + 0] * inv;
    g.y = tot80[tid * 5 + 1] * inv;
    g.z = tot80[tid * 5 + 2] * inv;
    g.w = tot80[tid * 5 + 3] * inv;
    sG[tid] = g;
    svalid[tid] = (c5 > 0.f && tid >= 1) ? 1.f : 0.f;
    if (blk == 0) {                    // publish for k_final
      ((float4*)(ws + WS_G))[b * MI + tid] = g;
      ws[WS_VAL + b * MI + tid] = svalid[tid];
    }
  }
  __syncthreads();

  // ---- pull pass: dist/log once per pixel, register accumulators ----
  float al[16];
#pragma unroll
  for (int m = 0; m < MI; m++) al[m] = 0.f;
  unsigned int cw[16];
#pragma unroll
  for (int m = 0; m < MI; m++) cw[m] = 0u;

  const float* s0 = outputs + (size_t)(b * 8 + 4) * NN;
  const int* ttb = gt_texts + (size_t)b * NN;

#pragma unroll
  for (int it = 0; it < 4; it++) {
    const int pix = blk * 4096 + it * 1024 + tid * 4;
    const int4 id4 = *(const int4*)(ttb + pix);
    const float4 x0 = *(const float4*)(s0 + pix);
    const float4 x1 = *(const float4*)(s0 + NN + pix);
    const float4 x2 = *(const float4*)(s0 + 2 * NN + pix);
    const float4 x3 = *(const float4*)(s0 + 3 * NN + pix);
#define SLOTP(IDC, XC)                                                       \
    {                                                                        \
      const int id = id4.IDC;                                                \
      const float4 g = sG[id];                                               \
      const float d0 = x0.XC - g.x, d1 = x1.XC - g.y;                        \
      const float d2 = x2.XC - g.z, d3 = x3.XC - g.w;                        \
      const float dist = sqrtf(d0*d0 + d1*d1 + d2*d2 + d3*d3 + CEPS) - 0.5f; \
      const float dm = fmaxf(dist, 0.f);                                     \
      const float l = __logf(1.f + dm * dm);                                 \
      _Pragma("unroll")                                                      \
      for (int m = 0; m < MI; m++) {                                         \
        const bool e = (id == m);                                            \
        cw[m] += (unsigned)__popcll(__ballot(e));    /* scalar pipe */       \
        al[m] += e ? l : 0.f;                                                \
      }                                                                      \
    }
    SLOTP(x, x) SLOTP(y, y) SLOTP(z, z) SLOTP(w, w)
#undef SLOTP
  }

  __syncthreads();                     // red[] reuse
#pragma unroll
  for (int v = 0; v < 16; v++) red[wv][lane][v] = al[v];
  if (lane == 0) {
#pragma unroll
    for (int m = 0; m < MI; m++) cbuf[wv][m] = (float)cw[m];
  }
  __syncthreads();
  if (tid < 32) {
    const int m = tid >> 1, c = tid & 1;
    float s = 0.f;
    if (c == 0) {
#pragma unroll
      for (int w = 0; w < 4; w++)
#pragma unroll 8
        for (int l = 0; l < 64; l++) s += red[w][(l + tid) & 63][m];
    } else {
      s = cbuf[0][m] + cbuf[1][m] + cbuf[2][m] + cbuf[3][m];
    }
    ws[WS_PP + (size_t)(b * GPB + blk) * 32 + tid] = s;   // plain store
  }
}

__global__ void k_final(const float* __restrict__ ws, float* __restrict__ out) {
  __shared__ float part[8][32];
  __shared__ float tot32[32];
  const int b = blockIdx.x, t = threadIdx.x;   // 256 threads, one block per b
  const int v = t & 31, h = t >> 5;            // 8 interleaved row groups
  float s = 0.f;
  for (int k = h; k < GPB; k += 8)
    s += ws[WS_PP + (size_t)(b * GPB + k) * 32 + v];
  part[h][v] = s;
  __syncthreads();
  if (t < 32) {
    float x = 0.f;
#pragma unroll
    for (int hh = 0; hh < 8; hh++) x += part[hh][t];
    tot32[t] = x;
  }
  __syncthreads();
  if (t == 0) {
    const float* G = ws + WS_G;
    const float* valid = ws + WS_VAL;
    float nv = 0.f;
    for (int m = 0; m < MI; m++) nv += valid[b * MI + m];
    float pull = 0.f;
    for (int m = 0; m < MI; m++) {
      const float per = tot32[m * 2] / fmaxf(tot32[m * 2 + 1], 1.f);
      pull += per * valid[b * MI + m];
    }
    pull /= fmaxf(nv, 1.f);
    float push = 0.f;
    for (int i = 0; i < MI; i++) {
      if (valid[b * MI + i] == 0.f) continue;
      for (int j = i + 1; j < MI; j++) {
        if (valid[b * MI + j] == 0.f) continue;
        float d2 = CEPS;
        for (int c = 0; c < 4; c++) {
          const float df = G[(b * MI + i) * 4 + c] - G[(b * MI + j) * 4 + c];
          d2 += df * df;
        }
        const float dk = sqrtf(d2);
        const float tq = fmaxf(3.f - dk, 0.f);
        push += log1pf(tq * tq);
      }
    }
    const float denom = nv * (nv - 1.f);
    push = (nv > 1.f) ? push / fmaxf(denom, 1.f) : 0.f;
    out[b] = pull;
    out[BB + b] = push;
  }
}

extern "C" void kernel_launch(void* const* d_in, const int* in_sizes, int n_in,
                              void* d_out, int out_size, void* d_ws, size_t ws_size,
                              hipStream_t stream) {
  const float* outputs = (const float*)d_in[0];
  const int* gt_texts = (const int*)d_in[1];
  const int* gt_kernels = (const int*)d_in[2];
  float* ws = (float*)d_ws;
  float* out = (float*)d_out;

  dim3 grid(GPB, BB);
  k_sums<<<grid, TPB, 0, stream>>>(outputs, gt_kernels, ws);
  k_pull<<<grid, TPB, 0, stream>>>(outputs, gt_texts, ws);
  k_final<<<BB, 256, 0, stream>>>(ws, out);
}

// Round 10
// 250.325 us; speedup vs baseline: 1.2923x; 1.0575x over previous
//
#include <hip/hip_runtime.h>
#include <math.h>

#define BB 8
#define MI 16
#define NN 409600          // 640*640
#define CEPS 1e-12f
#define GPB 200            // blocks per image; 2048 px/block
#define TPB 256

// ws float layout — no zero-init needed (every slot written before read):
//   PS:  k_sums partials [b][blk][v], v = m*5+c (c<4 channel sums, c=4 count)
//   G:   [b][m][4]  (float4 aligned)
//   VAL: [b][m]
//   PP:  k_pull partials [b][blk][v], v = m*2+c (c=0 loss sum, c=1 count)
#define WS_PS   0
#define WS_G    (BB*GPB*80)            // 128000
#define WS_VAL  (WS_G + BB*MI*4)
#define WS_PP   (WS_VAL + BB*MI)

// k_sums: wave w owns ids 4w..4w+3 (16 acc VGPRs). Every wave streams the
// whole 2048-px chunk (redundant reads are L1/L2-absorbed). Counts on the
// scalar pipe via ballot+popc. No atomics anywhere.
__global__ __launch_bounds__(TPB, 6) void k_sums(
    const float* __restrict__ outputs, const int* __restrict__ gt_kernels,
    float* __restrict__ ws) {
  __shared__ float red[4][64][17];     // stride-17: conflict-free columns
  __shared__ float cbuf[MI];
  const int b = blockIdx.y, blk = blockIdx.x, tid = threadIdx.x;
  const int wv = tid >> 6, lane = tid & 63;
  const int mb = wv * 4;

  float acc[16];                       // acc[c*4+j]: channel c, id mb+j
#pragma unroll
  for (int i = 0; i < 16; i++) acc[i] = 0.f;
  unsigned int cnt[4] = {0u, 0u, 0u, 0u};

  const float* s0 = outputs + (size_t)(b * 8 + 4) * NN;
  const int* gkb = gt_kernels + (size_t)b * NN;

#pragma unroll 2
  for (int it = 0; it < 8; it++) {
    const int pix = blk * 2048 + it * 256 + lane * 4;
    const int4 id4 = *(const int4*)(gkb + pix);
    const float4 x0 = *(const float4*)(s0 + pix);
    const float4 x1 = *(const float4*)(s0 + NN + pix);
    const float4 x2 = *(const float4*)(s0 + 2 * NN + pix);
    const float4 x3 = *(const float4*)(s0 + 3 * NN + pix);
#define SLOTK(IDC, XC)                                                       \
    {                                                                        \
      const int id = id4.IDC - mb;                                           \
      _Pragma("unroll")                                                      \
      for (int j = 0; j < 4; j++) {                                          \
        const bool e = (id == j);                                            \
        cnt[j] += (unsigned)__popcll(__ballot(e));   /* scalar pipe */       \
        const float f = e ? 1.f : 0.f;                                       \
        acc[0 * 4 + j] += f * x0.XC;                                         \
        acc[1 * 4 + j] += f * x1.XC;                                         \
        acc[2 * 4 + j] += f * x2.XC;                                         \
        acc[3 * 4 + j] += f * x3.XC;                                         \
      }                                                                      \
    }
    SLOTK(x, x) SLOTK(y, y) SLOTK(z, z) SLOTK(w, w)
#undef SLOTK
  }

  // flush: per-lane partials -> LDS, then 80 threads reduce 64 lanes each
#pragma unroll
  for (int v = 0; v < 16; v++) red[wv][lane][v] = acc[v];
  if (lane == 0) {
#pragma unroll
    for (int j = 0; j < 4; j++) cbuf[mb + j] = (float)cnt[j];
  }
  __syncthreads();
  if (tid < 80) {
    const int m = tid / 5, c = tid % 5;
    const int w = m >> 2, j = m & 3;
    float s;
    if (c < 4) {
      const int vi = c * 4 + j;
      s = 0.f;
#pragma unroll 8
      for (int l = 0; l < 64; l++) s += red[w][(l + tid) & 63][vi];
    } else {
      s = cbuf[m];
    }
    ws[WS_PS + (size_t)(b * GPB + blk) * 80 + tid] = s;   // contiguous per block
  }
}

__global__ void k_finG(float* __restrict__ ws) {
  __shared__ float part[5][80];
  __shared__ float tot[80];
  const int b = blockIdx.x, t = threadIdx.x;   // 400 threads
  const int v = t % 80, h = t / 80;            // h < 5, 40 blocks each
  float s = 0.f;
  const float* src = ws + WS_PS + (size_t)(b * GPB + h * 40) * 80 + v;
#pragma unroll                                  // FULL unroll: independent loads
  for (int k = 0; k < 40; k++) s += src[(size_t)k * 80];
  part[h][v] = s;
  __syncthreads();
  if (t < 80) tot[t] = part[0][t] + part[1][t] + part[2][t] + part[3][t] + part[4][t];
  __syncthreads();
  if (t < MI) {
    const float cnt = tot[t * 5 + 4];
    const float inv = 1.f / fmaxf(cnt, 1.f);
    float4 g;
    g.x = tot[t * 5 + 0] * inv;
    g.y = tot[t * 5 + 1] * inv;
    g.z = tot[t * 5 + 2] * inv;
    g.w = tot[t * 5 + 3] * inv;
    ((float4*)(ws + WS_G))[b * MI + t] = g;
    ws[WS_VAL + b * MI + t] = (cnt > 0.f && t >= 1) ? 1.f : 0.f;
  }
}

// k_pull: dist/log once per pixel; al[16] register accumulators (scalar l),
// counts on the scalar pipe. No atomics.
__global__ __launch_bounds__(TPB, 6) void k_pull(
    const float* __restrict__ outputs, const int* __restrict__ gt_texts,
    float* __restrict__ ws) {
  __shared__ float4 sG[MI];
  __shared__ float red[4][64][17];
  __shared__ float cbuf[4][MI];
  const int b = blockIdx.y, blk = blockIdx.x, tid = threadIdx.x;
  const int wv = tid >> 6, lane = tid & 63;
  if (tid < MI) sG[tid] = ((const float4*)(ws + WS_G))[b * MI + tid];
  __syncthreads();

  float al[16];
#pragma unroll
  for (int m = 0; m < MI; m++) al[m] = 0.f;
  unsigned int cw[16];
#pragma unroll
  for (int m = 0; m < MI; m++) cw[m] = 0u;

  const float* s0 = outputs + (size_t)(b * 8 + 4) * NN;
  const int* ttb = gt_texts + (size_t)b * NN;

#pragma unroll
  for (int it = 0; it < 2; it++) {
    const int pix = blk * 2048 + it * 1024 + tid * 4;
    const int4 id4 = *(const int4*)(ttb + pix);
    const float4 x0 = *(const float4*)(s0 + pix);
    const float4 x1 = *(const float4*)(s0 + NN + pix);
    const float4 x2 = *(const float4*)(s0 + 2 * NN + pix);
    const float4 x3 = *(const float4*)(s0 + 3 * NN + pix);
#define SLOTP(IDC, XC)                                                       \
    {                                                                        \
      const int id = id4.IDC;                                                \
      const float4 g = sG[id];                                               \
      const float d0 = x0.XC - g.x, d1 = x1.XC - g.y;                        \
      const float d2 = x2.XC - g.z, d3 = x3.XC - g.w;                        \
      const float dist = sqrtf(d0*d0 + d1*d1 + d2*d2 + d3*d3 + CEPS) - 0.5f; \
      const float dm = fmaxf(dist, 0.f);                                     \
      const float l = __logf(1.f + dm * dm);                                 \
      _Pragma("unroll")                                                      \
      for (int m = 0; m < MI; m++) {                                         \
        const bool e = (id == m);                                            \
        cw[m] += (unsigned)__popcll(__ballot(e));    /* scalar pipe */       \
        al[m] += e ? l : 0.f;                                                \
      }                                                                      \
    }
    SLOTP(x, x) SLOTP(y, y) SLOTP(z, z) SLOTP(w, w)
#undef SLOTP
  }

#pragma unroll
  for (int v = 0; v < 16; v++) red[wv][lane][v] = al[v];
  if (lane == 0) {
#pragma unroll
    for (int m = 0; m < MI; m++) cbuf[wv][m] = (float)cw[m];
  }
  __syncthreads();
  if (tid < 32) {
    const int m = tid >> 1, c = tid & 1;
    float s = 0.f;
    if (c == 0) {
#pragma unroll
      for (int w = 0; w < 4; w++)
#pragma unroll 8
        for (int l = 0; l < 64; l++) s += red[w][(l + tid) & 63][m];
    } else {
      s = cbuf[0][m] + cbuf[1][m] + cbuf[2][m] + cbuf[3][m];
    }
    ws[WS_PP + (size_t)(b * GPB + blk) * 32 + tid] = s;   // contiguous per block
  }
}

__global__ void k_final(const float* __restrict__ ws, float* __restrict__ out) {
  __shared__ float part[8][32];
  __shared__ float tot[32];
  const int b = blockIdx.x, t = threadIdx.x;   // 256 threads, one block per b
  const int v = t & 31, h = t >> 5;            // 8 chunks of 25 blocks
  float s = 0.f;
  const float* src = ws + WS_PP + (size_t)(b * GPB + h * 25) * 32 + v;
#pragma unroll                                  // FULL unroll: independent loads
  for (int k = 0; k < 25; k++) s += src[(size_t)k * 32];
  part[h][v] = s;
  __syncthreads();
  if (t < 32) {
    float x = 0.f;
#pragma unroll
    for (int hh = 0; hh < 8; hh++) x += part[hh][t];
    tot[t] = x;
  }
  __syncthreads();
  if (t == 0) {
    const float* G = ws + WS_G;
    const float* valid = ws + WS_VAL;
    float nv = 0.f;
    for (int m = 0; m < MI; m++) nv += valid[b * MI + m];
    float pull = 0.f;
    for (int m = 0; m < MI; m++) {
      const float per = tot[m * 2] / fmaxf(tot[m * 2 + 1], 1.f);
      pull += per * valid[b * MI + m];
    }
    pull /= fmaxf(nv, 1.f);
    float push = 0.f;
    for (int i = 0; i < MI; i++) {
      if (valid[b * MI + i] == 0.f) continue;
      for (int j = i + 1; j < MI; j++) {
        if (valid[b * MI + j] == 0.f) continue;
        float d2 = CEPS;
        for (int c = 0; c < 4; c++) {
          const float df = G[(b * MI + i) * 4 + c] - G[(b * MI + j) * 4 + c];
          d2 += df * df;
        }
        const float dk = sqrtf(d2);
        const float tt = fmaxf(3.f - dk, 0.f);
        push += log1pf(tt * tt);
      }
    }
    const float denom = nv * (nv - 1.f);
    push = (nv > 1.f) ? push / fmaxf(denom, 1.f) : 0.f;
    out[b] = pull;
    out[BB + b] = push;
  }
}

extern "C" void kernel_launch(void* const* d_in, const int* in_sizes, int n_in,
                              void* d_out, int out_size, void* d_ws, size_t ws_size,
                              hipStream_t stream) {
  const float* outputs = (const float*)d_in[0];
  const int* gt_texts = (const int*)d_in[1];
  const int* gt_kernels = (const int*)d_in[2];
  float* ws = (float*)d_ws;
  float* out = (float*)d_out;

  dim3 grid(GPB, BB);
  k_sums<<<grid, TPB, 0, stream>>>(outputs, gt_kernels, ws);
  k_finG<<<BB, 400, 0, stream>>>(ws);
  k_pull<<<grid, TPB, 0, stream>>>(outputs, gt_texts, ws);
  k_final<<<BB, 256, 0, stream>>>(ws, out);
}